// Round 17
// baseline (239.010 us; speedup 1.0000x reference)
//
#include <hip/hip_runtime.h>
#include <cstdint>

typedef __attribute__((ext_vector_type(8))) short bf16x8;
typedef __attribute__((ext_vector_type(4))) float f32x4;
typedef __attribute__((ext_vector_type(16))) float f32x16;
typedef __attribute__((ext_vector_type(4))) unsigned short u16x4;
typedef __attribute__((ext_vector_type(4))) unsigned int u32x4;
typedef unsigned short u16;

#define LOG2E 1.44269504088896340736f

__device__ __forceinline__ u16 f2bf(float f) {
  unsigned u = __builtin_bit_cast(unsigned, f);
  u += 0x7FFFu + ((u >> 16) & 1u);
  return (u16)(u >> 16);
}
__device__ __forceinline__ float bf2f(u16 h) {
  return __builtin_bit_cast(float, ((unsigned)h) << 16);
}

#define GLOAD_LDS16(g, l)                                                              \
  __builtin_amdgcn_global_load_lds((const __attribute__((address_space(1))) void*)(g), \
                                   (__attribute__((address_space(3))) void*)(l), 16, 0, 0)

// ------------- fused weight transpose: all 4 matrices in one launch -------------
__global__ __launch_bounds__(256) void k_transpose_all(
    const float* __restrict__ W0, u16* __restrict__ T0,   // W_attn 1024x3072
    const float* __restrict__ W1, u16* __restrict__ T1,   // W_proj 1024x1024
    const float* __restrict__ W2, u16* __restrict__ T2,   // W_fc   1024x4096
    const float* __restrict__ W3, u16* __restrict__ T3) { // W_mlp  4096x1024
  __shared__ float tile[32][33];
  int b = blockIdx.x;
  const float* W;
  u16* Wt;
  int K, N, nx;
  if (b < 3072)        { W = W0; Wt = T0; K = 1024; N = 3072; nx = 96; }
  else if (b < 4096)   { b -= 3072; W = W1; Wt = T1; K = 1024; N = 1024; nx = 32; }
  else if (b < 8192)   { b -= 4096; W = W2; Wt = T2; K = 1024; N = 4096; nx = 128; }
  else                 { b -= 8192; W = W3; Wt = T3; K = 4096; N = 1024; nx = 32; }
  const int n0 = (b % nx) * 32, k0 = (b / nx) * 32;
  const int tid = threadIdx.x;
  const int tx = tid & 31, ty = tid >> 5;
#pragma unroll
  for (int i = 0; i < 32; i += 8)
    tile[ty + i][tx] = W[(size_t)(k0 + ty + i) * N + n0 + tx];
  __syncthreads();
#pragma unroll
  for (int i = 0; i < 32; i += 8)
    Wt[(size_t)(n0 + ty + i) * K + k0 + tx] = f2bf(tile[tx][ty + i]);
}

// ---------------- LayerNorm [row][1024] -> bf16 (f32 or bf16 input) ----------------
template <bool INF32>
__global__ __launch_bounds__(256) void k_layernorm(
    const void* __restrict__ xin, const float* __restrict__ g,
    const float* __restrict__ b, u16* __restrict__ y) {
  const int row = blockIdx.x, tid = threadIdx.x;
  float v0, v1, v2, v3;
  if (INF32) {
    const float4 v = ((const float4*)((const float*)xin + (size_t)row * 1024))[tid];
    v0 = v.x; v1 = v.y; v2 = v.z; v3 = v.w;
  } else {
    const u16x4 v = ((const u16x4*)((const u16*)xin + (size_t)row * 1024))[tid];
    v0 = bf2f(v[0]); v1 = bf2f(v[1]); v2 = bf2f(v[2]); v3 = bf2f(v[3]);
  }
  float s = v0 + v1 + v2 + v3;
#pragma unroll
  for (int m = 1; m < 64; m <<= 1) s += __shfl_xor(s, m);
  __shared__ float ps[8];
  if ((tid & 63) == 0) ps[tid >> 6] = s;
  __syncthreads();
  const float mean = (ps[0] + ps[1] + ps[2] + ps[3]) * (1.0f / 1024.0f);
  const float d0 = v0 - mean, d1 = v1 - mean, d2 = v2 - mean, d3 = v3 - mean;
  float s2 = d0 * d0 + d1 * d1 + d2 * d2 + d3 * d3;
#pragma unroll
  for (int m = 1; m < 64; m <<= 1) s2 += __shfl_xor(s2, m);
  if ((tid & 63) == 0) ps[4 + (tid >> 6)] = s2;
  __syncthreads();
  const float var = (ps[4] + ps[5] + ps[6] + ps[7]) * (1.0f / 1024.0f);
  const float rstd = rsqrtf(var + 1e-5f);
  const float4 gv = ((const float4*)g)[tid];
  const float4 bv = ((const float4*)b)[tid];
  u16x4 o;
  o[0] = f2bf(d0 * rstd * gv.x + bv.x);
  o[1] = f2bf(d1 * rstd * gv.y + bv.y);
  o[2] = f2bf(d2 * rstd * gv.z + bv.z);
  o[3] = f2bf(d3 * rstd * gv.w + bv.w);
  *(u16x4*)(y + (size_t)row * 1024 + tid * 4) = o;
}

__device__ __forceinline__ float gelu_f(float x) {
  const float u = 0.7978845608028654f * (x + 0.044715f * x * x * x);
  const float e = exp2f(u * 2.8853900817779268f);  // e^{2u}
  const float t = 1.0f - 2.0f / (e + 1.0f);        // tanh(u)
  return 0.5f * x * (1.0f + t);
}

// ---------------- 128xBN GEMM, single-buffered; LDS-staged coalesced epilogue ------
template <int EPI, int BN>
__global__ __launch_bounds__(256, 4) void k_gemm_bt(
    const u16* __restrict__ A, const u16* __restrict__ Bt,
    const float* __restrict__ bias, const u16* __restrict__ resid,
    void* __restrict__ out, u16* __restrict__ vt, int M, int N, int K, int nbx) {
  constexpr int BM = 128;
  constexpr int LOOPB = (BM * 64 + BN * 64) * 2;
  constexpr int STP = BN + 8;
  constexpr int EPIB = (EPI == 1) ? 64 * 68 * 4 : BM * STP * 2;
  constexpr int SMB = LOOPB > EPIB ? LOOPB : EPIB;
  __shared__ char smem[SMB];
  u16* As = (u16*)smem;
  u16* Bs = (u16*)(smem + BM * 64 * 2);
  const int tid = threadIdx.x;
  const int wg = ((blockIdx.x & 7) * (gridDim.x >> 3)) + (blockIdx.x >> 3);
  const int bx = wg % nbx, by = wg / nbx;
  const int rowBase = by * BM, colBase = bx * BN;
  const int w = tid >> 6, l = tid & 63;
  const int wm = (BN == 128) ? (w >> 1) : w;
  const int wn = (BN == 128) ? (w & 1) : 0;
  constexpr int MR = (BN == 128) ? 4 : 2;
  constexpr int WROWS = (BN == 128) ? 64 : 32;
  const int lrow = l & 15, lg = l >> 4;
  const int srow = tid >> 3, sslot = tid & 7;

  const f32x4 fz = {0.f, 0.f, 0.f, 0.f};
  f32x4 acc[MR][4];
#pragma unroll
  for (int m = 0; m < MR; m++)
#pragma unroll
    for (int n = 0; n < 4; n++) acc[m][n] = fz;

  const int NT = K >> 6;
  for (int kt = 0; kt < NT; ++kt) {
#pragma unroll
    for (int i = 0; i < BM / 32; i++) {
      const int r = srow + 32 * i;
      const int gs = sslot ^ (r & 7);
      GLOAD_LDS16(A + (size_t)(rowBase + r) * K + kt * 64 + gs * 8,
                  (char*)As + i * 4096 + tid * 16);
    }
#pragma unroll
    for (int i = 0; i < BN / 32; i++) {
      const int r = srow + 32 * i;
      const int gs = sslot ^ (r & 7);
      GLOAD_LDS16(Bt + (size_t)(colBase + r) * K + kt * 64 + gs * 8,
                  (char*)Bs + i * 4096 + tid * 16);
    }
    __syncthreads();
#pragma unroll
    for (int kc = 0; kc < 2; kc++) {
      bf16x8 av[MR], bv[4];
#pragma unroll
      for (int m = 0; m < MR; m++) {
        const int r = wm * WROWS + m * 16 + lrow;
        const int sl = (kc * 4 + lg) ^ (r & 7);
        av[m] = *(const bf16x8*)((const char*)As + r * 128 + sl * 16);
      }
#pragma unroll
      for (int n = 0; n < 4; n++) {
        const int r = wn * 64 + n * 16 + lrow;
        const int sl = (kc * 4 + lg) ^ (r & 7);
        bv[n] = *(const bf16x8*)((const char*)Bs + r * 128 + sl * 16);
      }
#pragma unroll
      for (int m = 0; m < MR; m++)
#pragma unroll
        for (int n = 0; n < 4; n++)
          acc[m][n] = __builtin_amdgcn_mfma_f32_16x16x32_bf16(av[m], bv[n], acc[m][n], 0, 0, 0);
    }
    __syncthreads();
  }

  // ================= epilogue via LDS staging =================
  if (EPI == 1) {
    float* stgf = (float*)smem;
#pragma unroll
    for (int m = 0; m < MR; m++) {
      if (m) __syncthreads();
#pragma unroll
      for (int n = 0; n < 4; n++) {
        const int col = n * 16 + lrow;
        const float bval = bias[colBase + col];
        const int pr0 = wm * 16 + lg * 4;
#pragma unroll
        for (int r = 0; r < 4; r++) stgf[(pr0 + r) * 68 + col] = acc[m][n][r] + bval;
      }
      __syncthreads();
#pragma unroll
      for (int i = 0; i < 4; i++) {
        const int c = i * 256 + tid;
        const int pr = c >> 4, ch = c & 15;
        float4 d = *(float4*)(stgf + pr * 68 + ch * 4);
        const int grow = rowBase + ((pr >> 4) << 5) + m * 16 + (pr & 15);
        const size_t gidx = (size_t)grow * N + colBase + ch * 4;
        const u16x4 rr = *(const u16x4*)(resid + gidx);
        d.x += bf2f(rr[0]); d.y += bf2f(rr[1]); d.z += bf2f(rr[2]); d.w += bf2f(rr[3]);
        *(float4*)((float*)out + gidx) = d;
      }
    }
  } else {
    u16* stg = (u16*)smem;
    const bool vpath = (EPI == 3) && (colBase >= 2048);
#pragma unroll
    for (int n = 0; n < 4; n++) {
      const int col = wn * 64 + n * 16 + lrow;
      const float bval = bias[colBase + col];
#pragma unroll
      for (int m = 0; m < MR; m++) {
        const int lr0 = wm * WROWS + m * 16 + lg * 4;
#pragma unroll
        for (int r = 0; r < 4; r++) {
          float v = acc[m][n][r] + bval;
          if (EPI == 2) v = gelu_f(v);
          if (vpath)
            stg[col * STP + lr0 + r] = f2bf(v);
          else
            stg[(lr0 + r) * STP + col] = f2bf(v);
        }
      }
    }
    __syncthreads();
    if (vpath) {
      const int cb = colBase - 2048;
      const int bat = rowBase >> 11, tok0 = rowBase & 2047;
#pragma unroll
      for (int i = 0; i < 8; i++) {
        const int c = i * 256 + tid;
        const int cr = c >> 4, ch = c & 15;
        const u32x4 d = *(u32x4*)(stg + cr * STP + ch * 8);
        const int hh = (cb + cr) >> 6, dd = (cb + cr) & 63;
        *(u32x4*)(vt + ((size_t)(bat * 16 + hh) * 64 + dd) * 2048 + tok0 + ch * 8) = d;
      }
    } else {
      const int outN = (EPI == 3) ? 2048 : N;
      constexpr int CH = BN / 8;
#pragma unroll
      for (int i = 0; i < BM * CH / 256; i++) {
        const int c = i * 256 + tid;
        const int row = c / CH, ch = c % CH;
        u32x4 d = *(u32x4*)(stg + row * STP + ch * 8);
        const size_t gidx = (size_t)(rowBase + row) * outN + colBase + ch * 8;
        if (EPI == 4) {
          const u32x4 rr = *(const u32x4*)(resid + gidx);
#pragma unroll
          for (int j = 0; j < 4; j++) {
            const unsigned a = d[j], b = rr[j];
            const unsigned lo2 = (unsigned)f2bf(bf2f((u16)a) + bf2f((u16)b));
            const unsigned hi2 = (unsigned)f2bf(bf2f((u16)(a >> 16)) + bf2f((u16)(b >> 16)));
            d[j] = lo2 | (hi2 << 16);
          }
        }
        *(u32x4*)((u16*)out + gidx) = d;
      }
    }
  }
}

// ---------------- causal flash attention v8: KVBLK=128 + split-K pieces ----------
// bid -> (bh, qt, piece): u=bid>>5, bh=bid&31.
//   u in [0,8):   qt = 15-u,     piece 0 (tiles [0, ceil(nkt/2)))
//   u in [8,16):  qt = 15-(u-8), piece 1 (tiles [ceil(nkt/2), nkt), incl. diagonal)
//   u in [16,24): qt = 23-u,     full block (qt 7..0)
// Pieces write unnormalized f32 partials (O scaled 2^{-m*sc}, plus m,l per row);
// k_attn_combine merges. Critical path halves (16 -> 8 tiles per block).
__global__ __launch_bounds__(256, 2) void k_attention(
    const u16* __restrict__ qk, const u16* __restrict__ VT, u16* __restrict__ out,
    float* __restrict__ Op0, float* __restrict__ Op1,
    float2* __restrict__ ml0, float2* __restrict__ ml1) {
  const int S = 2048, E2 = 2048;
  const int bid = blockIdx.x;
  const int u = bid >> 5, bh = bid & 31;
  int qt, piece;
  if (u < 8)       { qt = 15 - u;      piece = 0; }
  else if (u < 16) { qt = 15 - (u - 8); piece = 1; }
  else             { qt = 23 - u;      piece = 2; }
  const int nkt = qt + 1;
  const int h0 = (nkt + 1) >> 1;
  const int t0 = (piece == 1) ? h0 : 0;
  const int t1 = (piece == 0) ? h0 : nkt;
  const int bat = bh >> 4, h = bh & 15;
  const u16* base = qk + (size_t)bat * S * E2;
  const u16* kbase = base + 1024 + h * 64;
  const u16* vbase = VT + (size_t)bh * 64 * S;
  const int tid = threadIdx.x, w = tid >> 6, l = tid & 63;
  const int l31 = l & 31, lh = l >> 5;
  __shared__ u16 Ks[2][128 * 64];  // [key][d-slot8]
  __shared__ u16 Vs[2][64 * 128];  // [d][tok-slot16]
  const int ksrow = tid >> 3;
  const int kgs = (tid & 7) ^ (ksrow & 7);
  const int vsrow = tid >> 4;
  const int vgs = (tid & 15) ^ (vsrow & 15);
  const float sc = 0.125f * LOG2E;
  const float RTHR = 8.0f / sc;

  auto STAGE = [&](int bufi, int kb) {
#pragma unroll
    for (int i = 0; i < 4; i++) {
      const int kr = ksrow + 32 * i;
      GLOAD_LDS16(kbase + (size_t)(kb + kr) * E2 + kgs * 8,
                  (char*)Ks[bufi] + i * 4096 + tid * 16);
      const int vr = vsrow + 16 * i;
      GLOAD_LDS16(vbase + (size_t)vr * S + kb + vgs * 8,
                  (char*)Vs[bufi] + i * 4096 + tid * 16);
    }
  };

  const int wq0 = qt * 128 + w * 32;
  const int qg = wq0 + l31;

  bf16x8 qf[4];
#pragma unroll
  for (int s = 0; s < 4; s++)
    qf[s] = *(const bf16x8*)(base + (size_t)qg * E2 + h * 64 + s * 16 + lh * 8);

  f32x16 o0, o1;
#pragma unroll
  for (int r = 0; r < 16; r++) { o0[r] = 0.f; o1[r] = 0.f; }
  float mrow = -1e30f, lsum = 0.f;

  STAGE(0, t0 * 128);
  __syncthreads();

  for (int t = t0; t < t1; t++) {
    const int cur = (t - t0) & 1;
    const int kb = t * 128;
    if (t + 1 < t1) STAGE(cur ^ 1, kb + 128);
    const u16* Kc = Ks[cur];
    const u16* Vc = Vs[cur];

    // ---- S^T = K Q^T over 4 key-quarters ----
    f32x16 sv[4];
#pragma unroll
    for (int j = 0; j < 4; j++)
#pragma unroll
      for (int r = 0; r < 16; r++) sv[j][r] = 0.f;
#pragma unroll
    for (int s = 0; s < 4; s++) {
      const int sl = s * 2 + lh;
#pragma unroll
      for (int j = 0; j < 4; j++) {
        const int rk = j * 32 + l31;
        const bf16x8 kf = *(const bf16x8*)(Kc + rk * 64 + ((sl ^ (rk & 7)) * 8));
        sv[j] = __builtin_amdgcn_mfma_f32_32x32x16_bf16(kf, qf[s], sv[j], 0, 0, 0);
      }
    }

    // ---- causal mask (diagonal tile only; always in piece 1 or full) ----
    if (t == nkt - 1) {
#pragma unroll
      for (int j = 0; j < 4; j++)
#pragma unroll
        for (int reg = 0; reg < 16; reg++) {
          const int kl = (reg & 3) + 8 * (reg >> 2) + 4 * lh;
          if (kb + j * 32 + kl > qg) sv[j][reg] = -1e30f;
        }
    }

    // ---- row max ----
    float tmax = sv[0][0];
#pragma unroll
    for (int j = 0; j < 4; j++)
#pragma unroll
      for (int reg = 0; reg < 16; reg++) tmax = fmaxf(tmax, sv[j][reg]);
    tmax = fmaxf(tmax, __shfl_xor(tmax, 32));

    // ---- defer-max online update ----
    if (!__all(tmax - mrow <= RTHR)) {
      const float mnew = fmaxf(mrow, tmax);
      const float corr = exp2f((mrow - mnew) * sc);
      lsum *= corr;
#pragma unroll
      for (int reg = 0; reg < 16; reg++) { o0[reg] *= corr; o1[reg] *= corr; }
      mrow = mnew;
    }
    const float msc = mrow * sc;

    // ---- P = exp2(s*sc - m*sc) in place; row-sum ----
    float rsum = 0.f;
#pragma unroll
    for (int j = 0; j < 4; j++)
#pragma unroll
      for (int reg = 0; reg < 16; reg++) {
        const float p = exp2f(fmaf(sv[j][reg], sc, -msc));
        sv[j][reg] = p;
        rsum += p;
      }
    rsum += __shfl_xor(rsum, 32);
    lsum += rsum;

    // ---- per key-quarter: pack to bf16, exchange halves, PV MFMA ----
    const bool lo = (lh == 0);
#pragma unroll
    for (int j = 0; j < 4; j++) {
      unsigned pk[8], ex[8];
#pragma unroll
      for (int jj = 0; jj < 8; jj++) {
        asm("v_cvt_pk_bf16_f32 %0, %1, %2"
            : "=v"(pk[jj])
            : "v"(sv[j][2 * jj]), "v"(sv[j][2 * jj + 1]));
        ex[jj] = (unsigned)__shfl_xor((int)pk[jj], 32);
      }
#pragma unroll
      for (int sl2 = 0; sl2 < 2; sl2++) {
        const int ks = j * 2 + sl2;
        const int j0 = sl2 * 4;
        const unsigned b0 = lo ? pk[j0 + 0] : ex[j0 + 2];
        const unsigned b1 = lo ? pk[j0 + 1] : ex[j0 + 3];
        const unsigned b2 = lo ? ex[j0 + 0] : pk[j0 + 2];
        const unsigned b3 = lo ? ex[j0 + 1] : pk[j0 + 3];
        const u32x4 pbu = {b0, b1, b2, b3};
        const bf16x8 pb = __builtin_bit_cast(bf16x8, pbu);
        const int svl = ks * 2 + lh;
        const int r0 = l31, r1 = 32 + l31;
        const bf16x8 v0 = *(const bf16x8*)(Vc + r0 * 128 + ((svl ^ (r0 & 15)) * 8));
        const bf16x8 v1 = *(const bf16x8*)(Vc + r1 * 128 + ((svl ^ (r1 & 15)) * 8));
        o0 = __builtin_amdgcn_mfma_f32_32x32x16_bf16(v0, pb, o0, 0, 0, 0);
        o1 = __builtin_amdgcn_mfma_f32_32x32x16_bf16(v1, pb, o1, 0, 0, 0);
      }
    }
    __syncthreads();
  }

  if (piece == 2) {
    // final store
    const float inv = 1.0f / lsum;
    const size_t orow = (size_t)(bat * S + qg) * 1024 + h * 64;
#pragma unroll
    for (int g = 0; g < 4; g++) {
      u16x4 s0, s1;
#pragma unroll
      for (int r = 0; r < 4; r++) {
        s0[r] = f2bf(o0[4 * g + r] * inv);
        s1[r] = f2bf(o1[4 * g + r] * inv);
      }
      const int d0 = 8 * g + 4 * lh;
      *(u16x4*)(out + orow + d0) = s0;
      *(u16x4*)(out + orow + 32 + d0) = s1;
    }
  } else {
    // partial store: rows qg >= 1024 only (qt >= 8)
    float* Op = piece ? Op1 : Op0;
    float2* mlp = piece ? ml1 : ml0;
    const size_t rix = (size_t)bh * 1024 + (qg - 1024);
    const size_t rbase = rix * 64;
#pragma unroll
    for (int g = 0; g < 4; g++) {
      const int d0 = 8 * g + 4 * lh;
      float4 a, b;
      a.x = o0[4 * g]; a.y = o0[4 * g + 1]; a.z = o0[4 * g + 2]; a.w = o0[4 * g + 3];
      b.x = o1[4 * g]; b.y = o1[4 * g + 1]; b.z = o1[4 * g + 2]; b.w = o1[4 * g + 3];
      *(float4*)(Op + rbase + d0) = a;
      *(float4*)(Op + rbase + 32 + d0) = b;
    }
    if (lh == 0) mlp[rix] = make_float2(mrow, lsum);
  }
}

// ---------------- split-K combine: rows qg in [1024,2048) per bh ----------------
__global__ __launch_bounds__(256) void k_attn_combine(
    const float* __restrict__ Op0, const float* __restrict__ Op1,
    const float2* __restrict__ ml0, const float2* __restrict__ ml1,
    u16* __restrict__ out) {
  const float sc = 0.125f * LOG2E;
  const int idx = blockIdx.x * 256 + threadIdx.x;
  const int d = idx & 63;
  const int row = idx >> 6;           // bh*1024 + (qg-1024)
  const int bh = row >> 10;
  const int qg = 1024 + (row & 1023);
  const int bat = bh >> 4, h = bh & 15;
  const float2 a = ml0[row], b = ml1[row];
  const float mf = fmaxf(a.x, b.x);
  const float w1 = exp2f((a.x - mf) * sc);
  const float w2 = exp2f((b.x - mf) * sc);
  const float linv = 1.0f / (a.y * w1 + b.y * w2);
  const float o = (Op0[(size_t)row * 64 + d] * w1 + Op1[(size_t)row * 64 + d] * w2) * linv;
  out[(size_t)(bat * 2048 + qg) * 1024 + h * 64 + d] = f2bf(o);
}

// ---------------- host launch ----------------
extern "C" void kernel_launch(void* const* d_in, const int* in_sizes, int n_in,
                              void* d_out, int out_size, void* d_ws, size_t ws_size,
                              hipStream_t stream) {
  (void)in_sizes; (void)n_in; (void)out_size; (void)ws_size;
  const float* x      = (const float*)d_in[0];
  const float* ln1_g  = (const float*)d_in[1];
  const float* ln1_b  = (const float*)d_in[2];
  const float* W_attn = (const float*)d_in[3];
  const float* b_attn = (const float*)d_in[4];
  const float* W_proj = (const float*)d_in[5];
  const float* b_proj = (const float*)d_in[6];
  const float* ln2_g  = (const float*)d_in[7];
  const float* ln2_b  = (const float*)d_in[8];
  const float* W_fc   = (const float*)d_in[9];
  const float* b_fc   = (const float*)d_in[10];
  const float* W_mlp  = (const float*)d_in[11];
  const float* b_mlp  = (const float*)d_in[12];

  const int M = 4096;  // B*S = 2*2048
  char* ws = (char*)d_ws;
  size_t off = 0;
  auto alloc = [&](size_t bytes) {
    void* p = ws + off;
    off += (bytes + 255) & ~(size_t)255;
    return p;
  };
  u16* WattnT = (u16*)alloc((size_t)3072 * 1024 * 2);
  u16* WprojT = (u16*)alloc((size_t)1024 * 1024 * 2);
  u16* WfcT   = (u16*)alloc((size_t)4096 * 1024 * 2);
  u16* WmlpT  = (u16*)alloc((size_t)1024 * 4096 * 2);
  u16* x1     = (u16*)alloc((size_t)M * 1024 * 2);
  u16* qkb    = (u16*)alloc((size_t)M * 2048 * 2);        // Q|K only
  u16* VT     = (u16*)alloc((size_t)32 * 64 * 2048 * 2);  // [b*h][d][tok]
  u16* attno  = (u16*)alloc((size_t)M * 1024 * 2);
  u16* x2     = (u16*)alloc((size_t)M * 1024 * 2);        // bf16 residual
  u16* x3     = (u16*)alloc((size_t)M * 1024 * 2);
  u16* hbuf   = (u16*)alloc((size_t)M * 4096 * 2);
  float*  Op0 = (float*)alloc((size_t)32 * 1024 * 64 * 4);   // split-K partials
  float*  Op1 = (float*)alloc((size_t)32 * 1024 * 64 * 4);
  float2* ml0 = (float2*)alloc((size_t)32 * 1024 * 8);
  float2* ml1 = (float2*)alloc((size_t)32 * 1024 * 8);

  const dim3 blk(256);
  k_transpose_all<<<dim3(12288), blk, 0, stream>>>(
      W_attn, WattnT, W_proj, WprojT, W_fc, WfcT, W_mlp, WmlpT);

  k_layernorm<true><<<M, blk, 0, stream>>>(x, ln1_g, ln1_b, x1);
  // QKV: BN=128, grid 24*32=768, EPI3 split epilogue
  k_gemm_bt<3, 128><<<dim3(768), blk, 0, stream>>>(
      x1, WattnT, b_attn, nullptr, qkb, VT, M, 3072, 1024, 24);
  // attention: 768 pieces (split-K for qt>=8) + combine for rows qg>=1024
  k_attention<<<dim3(768), blk, 0, stream>>>(qkb, VT, attno, Op0, Op1, ml0, ml1);
  k_attn_combine<<<dim3(32 * 1024 * 64 / 256), blk, 0, stream>>>(Op0, Op1, ml0, ml1, attno);
  // proj: BN=64, grid 512, EPI4 residual(x1) -> bf16 x2
  k_gemm_bt<4, 64><<<dim3(512), blk, 0, stream>>>(
      attno, WprojT, b_proj, x1, x2, nullptr, M, 1024, 1024, 16);
  k_layernorm<false><<<M, blk, 0, stream>>>(x2, ln2_g, ln2_b, x3);
  // FC: BN=128, grid 1024, EPI2 gelu
  k_gemm_bt<2, 128><<<dim3(1024), blk, 0, stream>>>(
      x3, WfcT, b_fc, nullptr, hbuf, nullptr, M, 4096, 1024, 32);
  // MLP-proj: BN=64, grid 512, EPI1 residual(x3) -> f32 d_out
  k_gemm_bt<1, 64><<<dim3(512), blk, 0, stream>>>(
      hbuf, WmlpT, b_mlp, x3, d_out, nullptr, M, 1024, 4096, 16);
}

// Round 18
// 235.714 us; speedup vs baseline: 1.0140x; 1.0140x over previous
//
#include <hip/hip_runtime.h>
#include <cstdint>

typedef __attribute__((ext_vector_type(8))) short bf16x8;
typedef __attribute__((ext_vector_type(4))) float f32x4;
typedef __attribute__((ext_vector_type(16))) float f32x16;
typedef __attribute__((ext_vector_type(4))) unsigned short u16x4;
typedef __attribute__((ext_vector_type(4))) unsigned int u32x4;
typedef unsigned short u16;

#define LOG2E 1.44269504088896340736f

__device__ __forceinline__ u16 f2bf(float f) {
  unsigned u = __builtin_bit_cast(unsigned, f);
  u += 0x7FFFu + ((u >> 16) & 1u);
  return (u16)(u >> 16);
}
__device__ __forceinline__ float bf2f(u16 h) {
  return __builtin_bit_cast(float, ((unsigned)h) << 16);
}

#define GLOAD_LDS16(g, l)                                                              \
  __builtin_amdgcn_global_load_lds((const __attribute__((address_space(1))) void*)(g), \
                                   (__attribute__((address_space(3))) void*)(l), 16, 0, 0)

// ------------- fused weight transpose: all 4 matrices in one launch -------------
__global__ __launch_bounds__(256) void k_transpose_all(
    const float* __restrict__ W0, u16* __restrict__ T0,   // W_attn 1024x3072
    const float* __restrict__ W1, u16* __restrict__ T1,   // W_proj 1024x1024
    const float* __restrict__ W2, u16* __restrict__ T2,   // W_fc   1024x4096
    const float* __restrict__ W3, u16* __restrict__ T3) { // W_mlp  4096x1024
  __shared__ float tile[32][33];
  int b = blockIdx.x;
  const float* W;
  u16* Wt;
  int K, N, nx;
  if (b < 3072)        { W = W0; Wt = T0; K = 1024; N = 3072; nx = 96; }
  else if (b < 4096)   { b -= 3072; W = W1; Wt = T1; K = 1024; N = 1024; nx = 32; }
  else if (b < 8192)   { b -= 4096; W = W2; Wt = T2; K = 1024; N = 4096; nx = 128; }
  else                 { b -= 8192; W = W3; Wt = T3; K = 4096; N = 1024; nx = 32; }
  const int n0 = (b % nx) * 32, k0 = (b / nx) * 32;
  const int tid = threadIdx.x;
  const int tx = tid & 31, ty = tid >> 5;
#pragma unroll
  for (int i = 0; i < 32; i += 8)
    tile[ty + i][tx] = W[(size_t)(k0 + ty + i) * N + n0 + tx];
  __syncthreads();
#pragma unroll
  for (int i = 0; i < 32; i += 8)
    Wt[(size_t)(n0 + ty + i) * K + k0 + tx] = f2bf(tile[tx][ty + i]);
}

// ---------------- LayerNorm [row][1024] -> bf16 (f32 or bf16 input) ----------------
template <bool INF32>
__global__ __launch_bounds__(256) void k_layernorm(
    const void* __restrict__ xin, const float* __restrict__ g,
    const float* __restrict__ b, u16* __restrict__ y) {
  const int row = blockIdx.x, tid = threadIdx.x;
  float v0, v1, v2, v3;
  if (INF32) {
    const float4 v = ((const float4*)((const float*)xin + (size_t)row * 1024))[tid];
    v0 = v.x; v1 = v.y; v2 = v.z; v3 = v.w;
  } else {
    const u16x4 v = ((const u16x4*)((const u16*)xin + (size_t)row * 1024))[tid];
    v0 = bf2f(v[0]); v1 = bf2f(v[1]); v2 = bf2f(v[2]); v3 = bf2f(v[3]);
  }
  float s = v0 + v1 + v2 + v3;
#pragma unroll
  for (int m = 1; m < 64; m <<= 1) s += __shfl_xor(s, m);
  __shared__ float ps[8];
  if ((tid & 63) == 0) ps[tid >> 6] = s;
  __syncthreads();
  const float mean = (ps[0] + ps[1] + ps[2] + ps[3]) * (1.0f / 1024.0f);
  const float d0 = v0 - mean, d1 = v1 - mean, d2 = v2 - mean, d3 = v3 - mean;
  float s2 = d0 * d0 + d1 * d1 + d2 * d2 + d3 * d3;
#pragma unroll
  for (int m = 1; m < 64; m <<= 1) s2 += __shfl_xor(s2, m);
  if ((tid & 63) == 0) ps[4 + (tid >> 6)] = s2;
  __syncthreads();
  const float var = (ps[4] + ps[5] + ps[6] + ps[7]) * (1.0f / 1024.0f);
  const float rstd = rsqrtf(var + 1e-5f);
  const float4 gv = ((const float4*)g)[tid];
  const float4 bv = ((const float4*)b)[tid];
  u16x4 o;
  o[0] = f2bf(d0 * rstd * gv.x + bv.x);
  o[1] = f2bf(d1 * rstd * gv.y + bv.y);
  o[2] = f2bf(d2 * rstd * gv.z + bv.z);
  o[3] = f2bf(d3 * rstd * gv.w + bv.w);
  *(u16x4*)(y + (size_t)row * 1024 + tid * 4) = o;
}

__device__ __forceinline__ float gelu_f(float x) {
  const float u = 0.7978845608028654f * (x + 0.044715f * x * x * x);
  const float e = exp2f(u * 2.8853900817779268f);  // e^{2u}
  const float t = 1.0f - 2.0f / (e + 1.0f);        // tanh(u)
  return 0.5f * x * (1.0f + t);
}

// ---------------- 128xBN GEMM, single-buffered; LDS-staged coalesced epilogue ------
template <int EPI, int BN>
__global__ __launch_bounds__(256, 4) void k_gemm_bt(
    const u16* __restrict__ A, const u16* __restrict__ Bt,
    const float* __restrict__ bias, const u16* __restrict__ resid,
    void* __restrict__ out, u16* __restrict__ vt, int M, int N, int K, int nbx) {
  constexpr int BM = 128;
  constexpr int LOOPB = (BM * 64 + BN * 64) * 2;
  constexpr int STP = BN + 8;
  constexpr int EPIB = (EPI == 1) ? 64 * 68 * 4 : BM * STP * 2;
  constexpr int SMB = LOOPB > EPIB ? LOOPB : EPIB;
  __shared__ char smem[SMB];
  u16* As = (u16*)smem;
  u16* Bs = (u16*)(smem + BM * 64 * 2);
  const int tid = threadIdx.x;
  const int wg = ((blockIdx.x & 7) * (gridDim.x >> 3)) + (blockIdx.x >> 3);
  const int bx = wg % nbx, by = wg / nbx;
  const int rowBase = by * BM, colBase = bx * BN;
  const int w = tid >> 6, l = tid & 63;
  const int wm = (BN == 128) ? (w >> 1) : w;
  const int wn = (BN == 128) ? (w & 1) : 0;
  constexpr int MR = (BN == 128) ? 4 : 2;
  constexpr int WROWS = (BN == 128) ? 64 : 32;
  const int lrow = l & 15, lg = l >> 4;
  const int srow = tid >> 3, sslot = tid & 7;

  const f32x4 fz = {0.f, 0.f, 0.f, 0.f};
  f32x4 acc[MR][4];
#pragma unroll
  for (int m = 0; m < MR; m++)
#pragma unroll
    for (int n = 0; n < 4; n++) acc[m][n] = fz;

  const int NT = K >> 6;
  for (int kt = 0; kt < NT; ++kt) {
#pragma unroll
    for (int i = 0; i < BM / 32; i++) {
      const int r = srow + 32 * i;
      const int gs = sslot ^ (r & 7);
      GLOAD_LDS16(A + (size_t)(rowBase + r) * K + kt * 64 + gs * 8,
                  (char*)As + i * 4096 + tid * 16);
    }
#pragma unroll
    for (int i = 0; i < BN / 32; i++) {
      const int r = srow + 32 * i;
      const int gs = sslot ^ (r & 7);
      GLOAD_LDS16(Bt + (size_t)(colBase + r) * K + kt * 64 + gs * 8,
                  (char*)Bs + i * 4096 + tid * 16);
    }
    __syncthreads();
#pragma unroll
    for (int kc = 0; kc < 2; kc++) {
      bf16x8 av[MR], bv[4];
#pragma unroll
      for (int m = 0; m < MR; m++) {
        const int r = wm * WROWS + m * 16 + lrow;
        const int sl = (kc * 4 + lg) ^ (r & 7);
        av[m] = *(const bf16x8*)((const char*)As + r * 128 + sl * 16);
      }
#pragma unroll
      for (int n = 0; n < 4; n++) {
        const int r = wn * 64 + n * 16 + lrow;
        const int sl = (kc * 4 + lg) ^ (r & 7);
        bv[n] = *(const bf16x8*)((const char*)Bs + r * 128 + sl * 16);
      }
#pragma unroll
      for (int m = 0; m < MR; m++)
#pragma unroll
        for (int n = 0; n < 4; n++)
          acc[m][n] = __builtin_amdgcn_mfma_f32_16x16x32_bf16(av[m], bv[n], acc[m][n], 0, 0, 0);
    }
    __syncthreads();
  }

  // ================= epilogue via LDS staging =================
  if (EPI == 1) {
    float* stgf = (float*)smem;
#pragma unroll
    for (int m = 0; m < MR; m++) {
      if (m) __syncthreads();
#pragma unroll
      for (int n = 0; n < 4; n++) {
        const int col = n * 16 + lrow;
        const float bval = bias[colBase + col];
        const int pr0 = wm * 16 + lg * 4;
#pragma unroll
        for (int r = 0; r < 4; r++) stgf[(pr0 + r) * 68 + col] = acc[m][n][r] + bval;
      }
      __syncthreads();
#pragma unroll
      for (int i = 0; i < 4; i++) {
        const int c = i * 256 + tid;
        const int pr = c >> 4, ch = c & 15;
        float4 d = *(float4*)(stgf + pr * 68 + ch * 4);
        const int grow = rowBase + ((pr >> 4) << 5) + m * 16 + (pr & 15);
        const size_t gidx = (size_t)grow * N + colBase + ch * 4;
        const u16x4 rr = *(const u16x4*)(resid + gidx);
        d.x += bf2f(rr[0]); d.y += bf2f(rr[1]); d.z += bf2f(rr[2]); d.w += bf2f(rr[3]);
        *(float4*)((float*)out + gidx) = d;
      }
    }
  } else {
    u16* stg = (u16*)smem;
    const bool vpath = (EPI == 3) && (colBase >= 2048);
#pragma unroll
    for (int n = 0; n < 4; n++) {
      const int col = wn * 64 + n * 16 + lrow;
      const float bval = bias[colBase + col];
#pragma unroll
      for (int m = 0; m < MR; m++) {
        const int lr0 = wm * WROWS + m * 16 + lg * 4;
#pragma unroll
        for (int r = 0; r < 4; r++) {
          float v = acc[m][n][r] + bval;
          if (EPI == 2) v = gelu_f(v);
          if (vpath)
            stg[col * STP + lr0 + r] = f2bf(v);
          else
            stg[(lr0 + r) * STP + col] = f2bf(v);
        }
      }
    }
    __syncthreads();
    if (vpath) {
      const int cb = colBase - 2048;
      const int bat = rowBase >> 11, tok0 = rowBase & 2047;
#pragma unroll
      for (int i = 0; i < 8; i++) {
        const int c = i * 256 + tid;
        const int cr = c >> 4, ch = c & 15;
        const u32x4 d = *(u32x4*)(stg + cr * STP + ch * 8);
        const int hh = (cb + cr) >> 6, dd = (cb + cr) & 63;
        *(u32x4*)(vt + ((size_t)(bat * 16 + hh) * 64 + dd) * 2048 + tok0 + ch * 8) = d;
      }
    } else {
      const int outN = (EPI == 3) ? 2048 : N;
      constexpr int CH = BN / 8;
#pragma unroll
      for (int i = 0; i < BM * CH / 256; i++) {
        const int c = i * 256 + tid;
        const int row = c / CH, ch = c % CH;
        u32x4 d = *(u32x4*)(stg + row * STP + ch * 8);
        const size_t gidx = (size_t)(rowBase + row) * outN + colBase + ch * 8;
        if (EPI == 4) {
          const u32x4 rr = *(const u32x4*)(resid + gidx);
#pragma unroll
          for (int j = 0; j < 4; j++) {
            const unsigned a = d[j], b = rr[j];
            const unsigned lo2 = (unsigned)f2bf(bf2f((u16)a) + bf2f((u16)b));
            const unsigned hi2 = (unsigned)f2bf(bf2f((u16)(a >> 16)) + bf2f((u16)(b >> 16)));
            d[j] = lo2 | (hi2 << 16);
          }
        }
        *(u32x4*)((u16*)out + gidx) = d;
      }
    }
  }
}

// ---------------- causal flash attention v7: KVBLK=128, R14 block map ----------
// (R16 best-measured configuration, reverted after split-K regression in R17.)
__global__ __launch_bounds__(256, 2) void k_attention(
    const u16* __restrict__ qk, const u16* __restrict__ VT, u16* __restrict__ out) {
  const int S = 2048, E2 = 2048;
  const int bid = blockIdx.x;
  const int qt = 15 - (bid >> 5);
  const int bh = bid & 31;
  const int bat = bh >> 4, h = bh & 15;
  const u16* base = qk + (size_t)bat * S * E2;
  const u16* kbase = base + 1024 + h * 64;
  const u16* vbase = VT + (size_t)bh * 64 * S;
  const int tid = threadIdx.x, w = tid >> 6, l = tid & 63;
  const int l31 = l & 31, lh = l >> 5;
  __shared__ u16 Ks[2][128 * 64];  // [key][d-slot8]
  __shared__ u16 Vs[2][64 * 128];  // [d][tok-slot16]
  const int ksrow = tid >> 3;
  const int kgs = (tid & 7) ^ (ksrow & 7);
  const int vsrow = tid >> 4;
  const int vgs = (tid & 15) ^ (vsrow & 15);
  const float sc = 0.125f * LOG2E;
  const float RTHR = 8.0f / sc;

  auto STAGE = [&](int bufi, int kb) {
#pragma unroll
    for (int i = 0; i < 4; i++) {
      const int kr = ksrow + 32 * i;  // key rows 0..127
      GLOAD_LDS16(kbase + (size_t)(kb + kr) * E2 + kgs * 8,
                  (char*)Ks[bufi] + i * 4096 + tid * 16);
      const int vr = vsrow + 16 * i;  // d rows 0..63
      GLOAD_LDS16(vbase + (size_t)vr * S + kb + vgs * 8,
                  (char*)Vs[bufi] + i * 4096 + tid * 16);
    }
  };

  const int wq0 = qt * 128 + w * 32;
  const int qg = wq0 + l31;
  const int nkt = qt + 1;  // 128-key tiles

  bf16x8 qf[4];
#pragma unroll
  for (int s = 0; s < 4; s++)
    qf[s] = *(const bf16x8*)(base + (size_t)qg * E2 + h * 64 + s * 16 + lh * 8);

  f32x16 o0, o1;
#pragma unroll
  for (int r = 0; r < 16; r++) { o0[r] = 0.f; o1[r] = 0.f; }
  float mrow = -1e30f, lsum = 0.f;

  STAGE(0, 0);
  __syncthreads();

  for (int t = 0; t < nkt; t++) {
    const int cur = t & 1;
    const int kb = t * 128;
    if (t + 1 < nkt) STAGE(cur ^ 1, kb + 128);
    const u16* Kc = Ks[cur];
    const u16* Vc = Vs[cur];

    // ---- S^T = K Q^T over 4 key-quarters ----
    f32x16 sv[4];
#pragma unroll
    for (int j = 0; j < 4; j++)
#pragma unroll
      for (int r = 0; r < 16; r++) sv[j][r] = 0.f;
#pragma unroll
    for (int s = 0; s < 4; s++) {
      const int sl = s * 2 + lh;
#pragma unroll
      for (int j = 0; j < 4; j++) {
        const int rk = j * 32 + l31;
        const bf16x8 kf = *(const bf16x8*)(Kc + rk * 64 + ((sl ^ (rk & 7)) * 8));
        sv[j] = __builtin_amdgcn_mfma_f32_32x32x16_bf16(kf, qf[s], sv[j], 0, 0, 0);
      }
    }

    // ---- causal mask (last tile only) ----
    if (t == nkt - 1) {
#pragma unroll
      for (int j = 0; j < 4; j++)
#pragma unroll
        for (int reg = 0; reg < 16; reg++) {
          const int kl = (reg & 3) + 8 * (reg >> 2) + 4 * lh;
          if (kb + j * 32 + kl > qg) sv[j][reg] = -1e30f;
        }
    }

    // ---- row max (63 in-lane fmax + 1 shfl) ----
    float tmax = sv[0][0];
#pragma unroll
    for (int j = 0; j < 4; j++)
#pragma unroll
      for (int reg = 0; reg < 16; reg++) tmax = fmaxf(tmax, sv[j][reg]);
    tmax = fmaxf(tmax, __shfl_xor(tmax, 32));

    // ---- defer-max online update ----
    if (!__all(tmax - mrow <= RTHR)) {
      const float mnew = fmaxf(mrow, tmax);
      const float corr = exp2f((mrow - mnew) * sc);
      lsum *= corr;
#pragma unroll
      for (int reg = 0; reg < 16; reg++) { o0[reg] *= corr; o1[reg] *= corr; }
      mrow = mnew;
    }
    const float msc = mrow * sc;

    // ---- P = exp2(s*sc - m*sc) in place; row-sum ----
    float rsum = 0.f;
#pragma unroll
    for (int j = 0; j < 4; j++)
#pragma unroll
      for (int reg = 0; reg < 16; reg++) {
        const float p = exp2f(fmaf(sv[j][reg], sc, -msc));
        sv[j][reg] = p;
        rsum += p;
      }
    rsum += __shfl_xor(rsum, 32);
    lsum += rsum;

    // ---- per key-quarter: pack to bf16, exchange halves, PV MFMA ----
    const bool lo = (lh == 0);
#pragma unroll
    for (int j = 0; j < 4; j++) {
      unsigned pk[8], ex[8];
#pragma unroll
      for (int jj = 0; jj < 8; jj++) {
        asm("v_cvt_pk_bf16_f32 %0, %1, %2"
            : "=v"(pk[jj])
            : "v"(sv[j][2 * jj]), "v"(sv[j][2 * jj + 1]));
        ex[jj] = (unsigned)__shfl_xor((int)pk[jj], 32);
      }
#pragma unroll
      for (int sl2 = 0; sl2 < 2; sl2++) {
        const int ks = j * 2 + sl2;
        const int j0 = sl2 * 4;
        const unsigned b0 = lo ? pk[j0 + 0] : ex[j0 + 2];
        const unsigned b1 = lo ? pk[j0 + 1] : ex[j0 + 3];
        const unsigned b2 = lo ? ex[j0 + 0] : pk[j0 + 2];
        const unsigned b3 = lo ? ex[j0 + 1] : pk[j0 + 3];
        const u32x4 pbu = {b0, b1, b2, b3};
        const bf16x8 pb = __builtin_bit_cast(bf16x8, pbu);
        const int svl = ks * 2 + lh;
        const int r0 = l31, r1 = 32 + l31;
        const bf16x8 v0 = *(const bf16x8*)(Vc + r0 * 128 + ((svl ^ (r0 & 15)) * 8));
        const bf16x8 v1 = *(const bf16x8*)(Vc + r1 * 128 + ((svl ^ (r1 & 15)) * 8));
        o0 = __builtin_amdgcn_mfma_f32_32x32x16_bf16(v0, pb, o0, 0, 0, 0);
        o1 = __builtin_amdgcn_mfma_f32_32x32x16_bf16(v1, pb, o1, 0, 0, 0);
      }
    }
    __syncthreads();  // drains prefetch (vmcnt 0) + fences LDS buffer reuse
  }

  const float inv = 1.0f / lsum;
  const size_t orow = (size_t)(bat * S + qg) * 1024 + h * 64;
#pragma unroll
  for (int g = 0; g < 4; g++) {
    u16x4 s0, s1;
#pragma unroll
    for (int r = 0; r < 4; r++) {
      s0[r] = f2bf(o0[4 * g + r] * inv);
      s1[r] = f2bf(o1[4 * g + r] * inv);
    }
    const int d0 = 8 * g + 4 * lh;
    *(u16x4*)(out + orow + d0) = s0;
    *(u16x4*)(out + orow + 32 + d0) = s1;
  }
}

// ---------------- host launch ----------------
extern "C" void kernel_launch(void* const* d_in, const int* in_sizes, int n_in,
                              void* d_out, int out_size, void* d_ws, size_t ws_size,
                              hipStream_t stream) {
  (void)in_sizes; (void)n_in; (void)out_size; (void)ws_size;
  const float* x      = (const float*)d_in[0];
  const float* ln1_g  = (const float*)d_in[1];
  const float* ln1_b  = (const float*)d_in[2];
  const float* W_attn = (const float*)d_in[3];
  const float* b_attn = (const float*)d_in[4];
  const float* W_proj = (const float*)d_in[5];
  const float* b_proj = (const float*)d_in[6];
  const float* ln2_g  = (const float*)d_in[7];
  const float* ln2_b  = (const float*)d_in[8];
  const float* W_fc   = (const float*)d_in[9];
  const float* b_fc   = (const float*)d_in[10];
  const float* W_mlp  = (const float*)d_in[11];
  const float* b_mlp  = (const float*)d_in[12];

  const int M = 4096;  // B*S = 2*2048
  char* ws = (char*)d_ws;
  size_t off = 0;
  auto alloc = [&](size_t bytes) {
    void* p = ws + off;
    off += (bytes + 255) & ~(size_t)255;
    return p;
  };
  u16* WattnT = (u16*)alloc((size_t)3072 * 1024 * 2);
  u16* WprojT = (u16*)alloc((size_t)1024 * 1024 * 2);
  u16* WfcT   = (u16*)alloc((size_t)4096 * 1024 * 2);
  u16* WmlpT  = (u16*)alloc((size_t)1024 * 4096 * 2);
  u16* x1     = (u16*)alloc((size_t)M * 1024 * 2);
  u16* qkb    = (u16*)alloc((size_t)M * 2048 * 2);        // Q|K only
  u16* VT     = (u16*)alloc((size_t)32 * 64 * 2048 * 2);  // [b*h][d][tok]
  u16* attno  = (u16*)alloc((size_t)M * 1024 * 2);
  u16* x2     = (u16*)alloc((size_t)M * 1024 * 2);        // bf16 residual
  u16* x3     = (u16*)alloc((size_t)M * 1024 * 2);
  u16* hbuf   = (u16*)alloc((size_t)M * 4096 * 2);

  const dim3 blk(256);
  k_transpose_all<<<dim3(12288), blk, 0, stream>>>(
      W_attn, WattnT, W_proj, WprojT, W_fc, WfcT, W_mlp, WmlpT);

  k_layernorm<true><<<M, blk, 0, stream>>>(x, ln1_g, ln1_b, x1);
  // QKV: BN=128, grid 24*32=768, EPI3 split epilogue
  k_gemm_bt<3, 128><<<dim3(768), blk, 0, stream>>>(
      x1, WattnT, b_attn, nullptr, qkb, VT, M, 3072, 1024, 24);
  k_attention<<<dim3(512), blk, 0, stream>>>(qkb, VT, attno);
  // proj: BN=64, grid 512, EPI4 residual(x1) -> bf16 x2
  k_gemm_bt<4, 64><<<dim3(512), blk, 0, stream>>>(
      attno, WprojT, b_proj, x1, x2, nullptr, M, 1024, 1024, 16);
  k_layernorm<false><<<M, blk, 0, stream>>>(x2, ln2_g, ln2_b, x3);
  // FC: BN=128, grid 1024, EPI2 gelu
  k_gemm_bt<2, 128><<<dim3(1024), blk, 0, stream>>>(
      x3, WfcT, b_fc, nullptr, hbuf, nullptr, M, 4096, 1024, 32);
  // MLP-proj: BN=64, grid 512, EPI1 residual(x3) -> f32 d_out
  k_gemm_bt<1, 64><<<dim3(512), blk, 0, stream>>>(
      hbuf, WmlpT, b_mlp, x3, d_out, nullptr, M, 1024, 4096, 16);
}